// Round 1
// baseline (142.426 us; speedup 1.0000x reference)
//
#include <hip/hip_runtime.h>
#include <hip/hip_bf16.h>

// TorchNeighborList on MI355X. Output: FLOAT32, pairs[K,2] | diff[K,3] | dist[K].
// R17: occupancy doubling. R16 counters: VALUBusy 18%, HBM 6% of peak,
// Occupancy 37.8% -- latency-bound, occupancy structurally capped at 50%
// (256 blocks x 1024 thr = 1 block/CU = 16/32 waves). Resources allow 2/CU:
// VGPR 60 <= 64, LDS 53.8KB <= 80KB. Grid -> 512x1024 (2 blocks/CU, 32
// waves/CU), JPT 6->3, __launch_bounds__(1024,8) pins VGPR<=64 so 2-block
// co-residency (required by the fence-free barrier) is guaranteed.
// Spin loops get bounded escapes: a residency surprise fails visibly, no hang.
// Ordering contract (passing since R3): atom i ascending -> 27-stencil
// cart3(1,1,1) row-major -> within cell t=i*27+p ascending.
// All f32 math via _rn intrinsics (no FMA contraction) to bit-match numpy/jax.

#define CUTOFF 5.0f
#define WEPS   1e-7f
#define PIMG   27
#define G      36
#define NCELLS (G*G*G)          // 46656
#define SLOT   16               // images per cell slab
#define NBLK   512
#define NTHR   1024
#define TOTT   (NBLK*NTHR)      // 524288
#define JPT    3                // consecutive (atom,stencil) idx per thread
#define PCH    (NTHR*JPT)       // 3072 idx per block
#define CAP    12               // cached pair addrs per thread
#define CSTR   13               // LDS stride (odd -> bank-conflict-free)
#define NGRP   16
#define BPG    (NBLK/NGRP)      // 32 blocks per barrier group
#define GSTR   64               // ints between group counters (256B lines)
#define IMAX   0x7FFFFFFF
#define SPINCAP (1<<20)         // bounded spin: fail visibly instead of hang

// grid barrier (used ONCE, after P1): release-RMW arrival tree; spin on
// RELAXED system-scope load; one fence after exit.
// Safe: 512 blocks x 2 blocks/CU, all co-resident (VGPR pinned <=64 by
// launch_bounds; LDS 2x53.8KB <= 160KB).
__device__ __forceinline__ void gsync(int* grp, int* top, int* rel, int phase) {
  __syncthreads();
  if (threadIdx.x == 0) {
    __threadfence();   // release
    int g = blockIdx.x & (NGRP - 1);
    if (__hip_atomic_fetch_add(&grp[g * GSTR], 1, __ATOMIC_RELEASE,
                               __HIP_MEMORY_SCOPE_AGENT) == BPG * phase - 1) {
      if (__hip_atomic_fetch_add(top, 1, __ATOMIC_RELEASE,
                                 __HIP_MEMORY_SCOPE_AGENT) == NGRP * phase - 1) {
        __hip_atomic_store(rel, phase, __ATOMIC_RELEASE, __HIP_MEMORY_SCOPE_SYSTEM);
      }
    }
    int guard = 0;
    while (__hip_atomic_load(rel, __ATOMIC_RELAXED, __HIP_MEMORY_SCOPE_SYSTEM) < phase) {
      __builtin_amdgcn_s_sleep(8);
      if (++guard > SPINCAP) break;   // safety escape (wrong output, no hang)
    }
    __threadfence();   // acquire
  }
  __syncthreads();
}

// block-wide exclusive scan over 1024 threads (16 waves). lds >= 18 ints.
__device__ __forceinline__ int block_exscan(int v, int* lds, int* total) {
  int tid = threadIdx.x, lane = tid & 63, wave = tid >> 6;
  int x = v;
#pragma unroll
  for (int off = 1; off < 64; off <<= 1) {
    int y = __shfl_up(x, off);
    if (lane >= off) x += y;
  }
  if (lane == 63) lds[wave] = x;
  __syncthreads();
  if (wave == 0) {
    int wv = (lane < 16) ? lds[lane] : 0;
#pragma unroll
    for (int off = 1; off < 16; off <<= 1) {
      int y = __shfl_up(wv, off);
      if (lane >= off) wv += y;
    }
    if (lane < 16) lds[lane] = wv;
  }
  __syncthreads();
  int wbase = (wave == 0) ? 0 : lds[wave - 1];
  *total = lds[15];
  __syncthreads();
  return wbase + x - v;
}

__device__ __forceinline__ void inv_diag3(const float* __restrict__ cell, float inv[9]) {
  float c[9];
#pragma unroll
  for (int i = 0; i < 9; i++) c[i] = cell[i];
  float a00=c[0],a01=c[1],a02=c[2],a10=c[3],a11=c[4],a12=c[5],a20=c[6],a21=c[7],a22=c[8];
  float m00 = __fsub_rn(__fmul_rn(a11,a22), __fmul_rn(a12,a21));
  float m01 = __fsub_rn(__fmul_rn(a10,a22), __fmul_rn(a12,a20));
  float m02 = __fsub_rn(__fmul_rn(a10,a21), __fmul_rn(a11,a20));
  float det = __fadd_rn(__fsub_rn(__fmul_rn(a00,m00), __fmul_rn(a01,m01)), __fmul_rn(a02,m02));
  inv[0] = __fdiv_rn(m00, det);
  inv[1] = __fdiv_rn(__fsub_rn(__fmul_rn(a02,a21), __fmul_rn(a01,a22)), det);
  inv[2] = __fdiv_rn(__fsub_rn(__fmul_rn(a01,a12), __fmul_rn(a02,a11)), det);
  inv[3] = __fdiv_rn(__fsub_rn(__fmul_rn(a12,a20), __fmul_rn(a10,a22)), det);
  inv[4] = __fdiv_rn(__fsub_rn(__fmul_rn(a00,a22), __fmul_rn(a02,a20)), det);
  inv[5] = __fdiv_rn(__fsub_rn(__fmul_rn(a02,a10), __fmul_rn(a00,a12)), det);
  inv[6] = __fdiv_rn(m02, det);
  inv[7] = __fdiv_rn(__fsub_rn(__fmul_rn(a01,a20), __fmul_rn(a00,a21)), det);
  inv[8] = __fdiv_rn(__fsub_rn(__fmul_rn(a00,a11), __fmul_rn(a01,a10)), det);
}

// per-axis image options; ascending p-component so combos enumerate in
// ascending stencil index p (reference stable-sort key order).
__device__ __forceinline__ int axis_opts(float w, float cdiag, int* pcomp, int* cellv,
                                         float* shv) {
  int cc = (int)floorf(__fdiv_rn(w, CUTOFF));
  int k = 0;
  if (cc >= 29) {
    float wp = __fsub_rn(w, cdiag);
    int c2 = (int)floorf(__fdiv_rn(wp, CUTOFF)) + 2;
    if ((unsigned)c2 < G) { pcomp[k] = 0; cellv[k] = c2; shv[k] = __fsub_rn(0.0f, cdiag); k++; }
  }
  pcomp[k] = 1; cellv[k] = cc + 2; shv[k] = 0.0f; k++;
  if (cc <= 2) {
    float wp = __fadd_rn(w, cdiag);
    int c2 = (int)floorf(__fdiv_rn(wp, CUTOFF)) + 2;
    if ((unsigned)c2 < G) { pcomp[k] = 2; cellv[k] = c2; shv[k] = cdiag; k++; }
  }
  return k;
}

// pair test (bit-exact reference math)
__device__ __forceinline__ bool dist_ok(float4 f, float4 w) {
  float ax = __fsub_rn(f.x, w.x), ay = __fsub_rn(f.y, w.y), az = __fsub_rn(f.z, w.z);
  float d = __fsqrt_rn(__fadd_rn(__fadd_rn(__fmul_rn(ax, ax), __fmul_rn(ay, ay)),
                                 __fmul_rn(az, az)));
  return (d < CUTOFF && d > 0.01f);
}

// match mask for one (atom, cell) visit (fallback path, cnt>4)
__device__ __forceinline__ unsigned match_mask(const float4* __restrict__ cdata,
                                               int base, int cnt, float4 w) {
  unsigned mask = 0;
  for (int q = 0; q < cnt; q++)
    if (dist_ok(cdata[base + q], w)) mask |= 1u << q;
  return mask;
}

// extract min-t bit from mask (entries are cache-hot 4B .w reads)
__device__ __forceinline__ int pick_min_t(const float4* __restrict__ cdata, int base,
                                          unsigned mask) {
  int bq = -1, bt = IMAX;
  for (unsigned m2 = mask; m2; m2 &= m2 - 1) {
    int q = __builtin_ctz(m2);
    int t = __float_as_int(cdata[base + q].w);
    if (t < bt) { bt = t; bq = q; }
  }
  return bq;
}

__device__ __forceinline__ void cswap(int& a, int& b) {
  int lo = min(a, b), hi = max(a, b);
  a = lo; b = hi;
}

__global__ void __launch_bounds__(NTHR, 8)   // 8 waves/SIMD -> VGPR<=64 -> 2 blocks/CU
k_fused(const float* __restrict__ pos, const float* __restrict__ cell,
        float* __restrict__ out, int n, int K,
        int* grp, int* top, int* rel, int* fill,
        float4* wrapped, int* pubSum, float4* cdata) {
  __shared__ int lds[32];
  __shared__ int pcache[NTHR * CSTR];    // 53 KB: pair slab-addresses, stride 13
  const int tid = threadIdx.x, blk = blockIdx.x;
  const int n27 = n * PIMG;

  // ---- P1: wrap + slab scatter, block-chunked (all 512 blocks share work) ----
  const int CH = (n + NBLK - 1) / NBLK;          // atoms per block (98)
  const int ai = blk * CH + tid;                 // coalesced within block
  if (tid < CH && ai < n) {
    float inv[9];
    inv_diag3(cell, inv);
    float px = pos[3*ai], py = pos[3*ai+1], pz = pos[3*ai+2];
    float m[3];
#pragma unroll
    for (int col = 0; col < 3; col++) {
      float s = __fadd_rn(__fadd_rn(__fmul_rn(px, inv[col]), __fmul_rn(py, inv[3+col])),
                          __fmul_rn(pz, inv[6+col]));
      s = __fadd_rn(s, WEPS);
      float t = __fsub_rn(s, floorf(s));
      m[col] = __fsub_rn(t, WEPS);
    }
    float wx = __fadd_rn(__fadd_rn(__fmul_rn(m[0], cell[0]), __fmul_rn(m[1], cell[3])),
                         __fmul_rn(m[2], cell[6]));
    float wy = __fadd_rn(__fadd_rn(__fmul_rn(m[0], cell[1]), __fmul_rn(m[1], cell[4])),
                         __fmul_rn(m[2], cell[7]));
    float wz = __fadd_rn(__fadd_rn(__fmul_rn(m[0], cell[2]), __fmul_rn(m[1], cell[5])),
                         __fmul_rn(m[2], cell[8]));
    wrapped[ai] = make_float4(wx, wy, wz, 0.0f);
    int px_[2], py_[2], pz_[2], cx_[2], cy_[2], cz_[2];
    float sx_[2], sy_[2], sz_[2];
    int nx = axis_opts(wx, cell[0], px_, cx_, sx_);
    int ny = axis_opts(wy, cell[4], py_, cy_, sy_);
    int nz = axis_opts(wz, cell[8], pz_, cz_, sz_);
    for (int a = 0; a < nx; a++)
      for (int b = 0; b < ny; b++)
        for (int c = 0; c < nz; c++) {
          int cid = (cx_[a] * G + cy_[b]) * G + cz_[c];
          int p = (px_[a] * 3 + py_[b]) * 3 + pz_[c];
          int slot = atomicAdd(&fill[cid], 1);
          if (slot < SLOT)
            cdata[cid * SLOT + slot] =
                make_float4(__fadd_rn(wx, sx_[a]), __fadd_rn(wy, sy_[b]),
                            __fadd_rn(wz, sz_[c]), __int_as_float(ai * PIMG + p));
        }
  }
  gsync(grp, top, rel, 1);   // the ONLY full barrier

  // ---- P2: pair count + LDS addr cache; branch-free 4-load visits ----
  const int tbase = blk * PCH + tid * JPT;
  const int i0 = min(tbase, n27 - 1) / PIMG;
  const int i1 = min(tbase + JPT - 1, n27 - 1) / PIMG;
  const float4 w0 = wrapped[i0];                // independent loads
  const float4 w1 = wrapped[i1];
  const int cx0 = (int)floorf(__fdiv_rn(w0.x, CUTOFF)) + 2;
  const int cy0 = (int)floorf(__fdiv_rn(w0.y, CUTOFF)) + 2;
  const int cz0 = (int)floorf(__fdiv_rn(w0.z, CUTOFF)) + 2;
  const int cx1 = (int)floorf(__fdiv_rn(w1.x, CUTOFF)) + 2;
  const int cy1 = (int)floorf(__fdiv_rn(w1.y, CUTOFF)) + 2;
  const int cz1 = (int)floorf(__fdiv_rn(w1.z, CUTOFF)) + 2;
  int bases[JPT], cnts[JPT];
#pragma unroll
  for (int j = 0; j < JPT; j++) {               // independent fill loads
    int idx = tbase + j;
    bool valid = idx < n27;
    int ic = valid ? idx / PIMG : i0;
    int s27 = valid ? idx - ic * PIMG : 0;
    bool a0 = (ic == i0);
    int dx = s27 / 9 - 1, dy = (s27 / 3) % 3 - 1, dz = s27 % 3 - 1;
    int cx = (a0 ? cx0 : cx1) + dx, cy = (a0 ? cy0 : cy1) + dy, cz = (a0 ? cz0 : cz1) + dz;
    int cid = (cx * G + cy) * G + cz;
    bases[j] = cid * SLOT;
    cnts[j] = valid ? min(fill[cid], SLOT) : 0;
  }
  int tcnt = 0, c0 = 0;
#pragma unroll
  for (int j = 0; j < JPT; j++) {
    bool a0 = (tbase + j) < (i0 + 1) * PIMG;
    float4 w = a0 ? w0 : w1;
    int base = bases[j], cnt = cnts[j];
    if (cnt > 0) {
      if (cnt <= 4) {
        // common path (98%): 4 unconditional independent loads from the
        // 64B-aligned slab head (over-read is same-line; garbage masked).
        float4 f0 = cdata[base + 0];
        float4 f1 = cdata[base + 1];
        float4 f2 = cdata[base + 2];
        float4 f3 = cdata[base + 3];
        // packed key t*16+q: preserves t order (t unique); IMAX = no match
        int a = (cnt > 0 && dist_ok(f0, w)) ? (__float_as_int(f0.w) * 16 + 0) : IMAX;
        int b = (cnt > 1 && dist_ok(f1, w)) ? (__float_as_int(f1.w) * 16 + 1) : IMAX;
        int c = (cnt > 2 && dist_ok(f2, w)) ? (__float_as_int(f2.w) * 16 + 2) : IMAX;
        int d = (cnt > 3 && dist_ok(f3, w)) ? (__float_as_int(f3.w) * 16 + 3) : IMAX;
        cswap(a, b); cswap(c, d); cswap(a, c); cswap(b, d); cswap(b, c);
        if (a != IMAX) { if (tcnt < CAP) pcache[tid * CSTR + tcnt] = base + (a & 15); tcnt++; }
        if (b != IMAX) { if (tcnt < CAP) pcache[tid * CSTR + tcnt] = base + (b & 15); tcnt++; }
        if (c != IMAX) { if (tcnt < CAP) pcache[tid * CSTR + tcnt] = base + (c & 15); tcnt++; }
        if (d != IMAX) { if (tcnt < CAP) pcache[tid * CSTR + tcnt] = base + (d & 15); tcnt++; }
      } else {
        // rare path (~2%): scalar loop + min-t selection (R11 exact)
        unsigned mask = match_mask(cdata, base, cnt, w);
        while (mask) {
          int bq = pick_min_t(cdata, base, mask);
          mask &= ~(1u << bq);
          if (tcnt < CAP) pcache[tid * CSTR + tcnt] = base + bq;
          tcnt++;
        }
      }
    }
    if (a0) c0 = tcnt;
  }
  int btotal;
  const int texcl = block_exscan(tcnt, lds, &btotal);   // register-carried offset

  // ---- fence-free all-gather of NBLK block sums (replaces barrier 2) ----
  // Only block sums cross blocks here; they travel through system-scope
  // atomics (coherent bypass). cdata/fill/wrapped were fenced at barrier 1 and
  // are unmodified since; pcache is per-block LDS. No memory fence needed ->
  // L2 stays hot into emit.
  if (tid == 0)
    __hip_atomic_store(&pubSum[blk], btotal + 1, __ATOMIC_RELAXED,
                       __HIP_MEMORY_SCOPE_SYSTEM);
  int v = 0;
  if (tid < NBLK) {
    int guard = 0;
    while ((v = __hip_atomic_load(&pubSum[tid], __ATOMIC_RELAXED,
                                  __HIP_MEMORY_SCOPE_SYSTEM)) == 0) {
      __builtin_amdgcn_s_sleep(2);
      if (++guard > SPINCAP) break;   // safety escape (wrong output, no hang)
    }
    v -= 1;
  }
  int obase, M;
  {
    int total;
    int ex = block_exscan(v, lds, &total);
    if (tid == blk) lds[16] = ex;       // this block's base (exactly one writer)
    if (tid == 0)   lds[17] = total;
    __syncthreads();
    obase = lds[16];
    M = lds[17];
  }

  // ---- P3: emit from LDS cache ----
  if (blk == 0 && tid == 0 && M != K) {
    float code = (M < K) ? (1000000.0f + (float)min(K - M, 100000))
                         : (2000000.0f + (float)min(M - K, 100000));
    for (int t = 0; t < 256; t++) out[t] = code;
  }
  int o = texcl + obase;
  if (tcnt <= CAP) {
    // fast path: K scattered reloads only (addresses cached in LDS; L2-hot)
    for (int k = 0; k < tcnt; k++) {
      float4 f = cdata[pcache[tid * CSTR + k]];
      bool a0 = (k < c0);
      float4 w = a0 ? w0 : w1;
      int i = a0 ? i0 : i1;
      float ax = __fsub_rn(f.x, w.x), ay = __fsub_rn(f.y, w.y), az = __fsub_rn(f.z, w.z);
      float d = __fsqrt_rn(__fadd_rn(__fadd_rn(__fmul_rn(ax, ax), __fmul_rn(ay, ay)),
                                     __fmul_rn(az, az)));
      if (o >= 0 && o < K) {
        int tt = __float_as_int(f.w);
        ((float2*)out)[o] = make_float2((float)i, (float)(tt / PIMG));
        size_t db = (size_t)2 * K + (size_t)3 * o;
        out[db]     = ax;
        out[db + 1] = ay;
        out[db + 2] = az;
        out[(size_t)5 * K + o] = d;
      }
      o++;
    }
  } else {
    // overflow fallback (P~1e-10): full re-traversal with same selection order
#pragma unroll
    for (int j = 0; j < JPT; j++) {
      bool a0 = (tbase + j) < (i0 + 1) * PIMG;
      float4 w = a0 ? w0 : w1;
      int i = a0 ? i0 : i1;
      int base = bases[j];
      unsigned mask = match_mask(cdata, base, cnts[j], w);
      while (mask) {
        int bq = pick_min_t(cdata, base, mask);
        mask &= ~(1u << bq);
        float4 f = cdata[base + bq];
        float ax = __fsub_rn(f.x, w.x), ay = __fsub_rn(f.y, w.y), az = __fsub_rn(f.z, w.z);
        float d = __fsqrt_rn(__fadd_rn(__fadd_rn(__fmul_rn(ax, ax), __fmul_rn(ay, ay)),
                                       __fmul_rn(az, az)));
        if (o >= 0 && o < K) {
          int tt = __float_as_int(f.w);
          ((float2*)out)[o] = make_float2((float)i, (float)(tt / PIMG));
          size_t db = (size_t)2 * K + (size_t)3 * o;
          out[db]     = ax;
          out[db + 1] = ay;
          out[db + 2] = az;
          out[(size_t)5 * K + o] = d;
        }
        o++;
      }
    }
  }
}

extern "C" void kernel_launch(void* const* d_in, const int* in_sizes, int n_in,
                              void* d_out, int out_size, void* d_ws, size_t ws_size,
                              hipStream_t stream) {
  const float* pos  = (const float*)d_in[0];
  const float* cell = (const float*)d_in[1];
  float* out = (float*)d_out;
  int n = in_sizes[0] / 3;
  int K = out_size / 6;

  char* ws = (char*)d_ws;
  size_t off = 0;
  auto alloc = [&](size_t bytes) -> char* {
    char* p = ws + off;
    off = (off + bytes + 255) & ~(size_t)255;
    return p;
  };
  // zeroed region first (single small memset): grp | top | rel | pubSum | fill
  int*    grp      = (int*)alloc((size_t)NGRP * GSTR * 4);   // 4 KB, 16 lines
  int*    top      = (int*)alloc(256);
  int*    rel      = (int*)alloc(256);
  int*    pubSum   = (int*)alloc((size_t)NBLK * 4);
  int*    fill     = (int*)alloc((size_t)NCELLS * 4);        // 187 KB
  size_t  zbytes   = off;
  float4* wrapped  = (float4*)alloc((size_t)n * 16);
  float4* cdata    = (float4*)alloc((size_t)NCELLS * SLOT * 16);   // 11.9 MB
  if (off > ws_size) return;

  (void)hipMemsetAsync(ws, 0, zbytes, stream);
  k_fused<<<NBLK, NTHR, 0, stream>>>(pos, cell, out, n, K, grp, top, rel, fill,
                                     wrapped, pubSum, cdata);
}

// Round 2
// 132.286 us; speedup vs baseline: 1.0766x; 1.0766x over previous
//
#include <hip/hip_runtime.h>
#include <hip/hip_bf16.h>

// TorchNeighborList on MI355X. Output: FLOAT32, pairs[K,2] | diff[K,3] | dist[K].
// R18: scattered-request halving. R17 post-mortem: occupancy 2x (84%) gave ZERO
// extra VALU issue and +25% dur -> bottleneck is per-CU vector-memory request
// processing (64 divergent lines per wave instr), not wave latency. Revert to
// R16 launch shape (256x1024, JPT=6, 70us proven). New: cdata is memset to
// 0xFF each launch -> unwritten slots are NaN-poisoned; dist_ok(NaN)=false
// filters them for free, so the P2 fast path no longer reads fill[] at all
// (was 1.35M extra scattered 4B loads, half of all scattered requests).
// Overflow (cnt>4, ~2%) detected via slot3.t >= 0, only then fill is read.
// Slab loads are now unconditional (clamped base) -> compiler batches all
// 24 float4 loads per thread for max MLP.
// Ordering contract (passing since R3): atom i ascending -> 27-stencil
// cart3(1,1,1) row-major -> within cell t=i*27+p ascending.
// All f32 math via _rn intrinsics (no FMA contraction) to bit-match numpy/jax.

#define CUTOFF 5.0f
#define WEPS   1e-7f
#define PIMG   27
#define G      36
#define NCELLS (G*G*G)          // 46656
#define SLOT   16               // images per cell slab
#define NBLK   256
#define NTHR   1024
#define TOTT   (NBLK*NTHR)      // 262144
#define JPT    6                // consecutive (atom,stencil) idx per thread
#define PCH    (NTHR*JPT)       // 6144 idx per block
#define CAP    12               // cached pair addrs per thread
#define CSTR   13               // LDS stride (odd -> bank-conflict-free)
#define NGRP   16
#define BPG    (NBLK/NGRP)      // 16 blocks per barrier group
#define GSTR   64               // ints between group counters (256B lines)
#define IMAX   0x7FFFFFFF
#define SPINCAP (1<<20)         // bounded spin: fail visibly instead of hang

// grid barrier (used ONCE, after P1): release-RMW arrival tree; spin on
// RELAXED system-scope load; one fence after exit.
// Safe: 256 blocks x 1 block/CU, all co-resident.
__device__ __forceinline__ void gsync(int* grp, int* top, int* rel, int phase) {
  __syncthreads();
  if (threadIdx.x == 0) {
    __threadfence();   // release
    int g = blockIdx.x & (NGRP - 1);
    if (__hip_atomic_fetch_add(&grp[g * GSTR], 1, __ATOMIC_RELEASE,
                               __HIP_MEMORY_SCOPE_AGENT) == BPG * phase - 1) {
      if (__hip_atomic_fetch_add(top, 1, __ATOMIC_RELEASE,
                                 __HIP_MEMORY_SCOPE_AGENT) == NGRP * phase - 1) {
        __hip_atomic_store(rel, phase, __ATOMIC_RELEASE, __HIP_MEMORY_SCOPE_SYSTEM);
      }
    }
    int guard = 0;
    while (__hip_atomic_load(rel, __ATOMIC_RELAXED, __HIP_MEMORY_SCOPE_SYSTEM) < phase) {
      __builtin_amdgcn_s_sleep(8);
      if (++guard > SPINCAP) break;   // safety escape (wrong output, no hang)
    }
    __threadfence();   // acquire
  }
  __syncthreads();
}

// block-wide exclusive scan over 1024 threads (16 waves). lds >= 18 ints.
__device__ __forceinline__ int block_exscan(int v, int* lds, int* total) {
  int tid = threadIdx.x, lane = tid & 63, wave = tid >> 6;
  int x = v;
#pragma unroll
  for (int off = 1; off < 64; off <<= 1) {
    int y = __shfl_up(x, off);
    if (lane >= off) x += y;
  }
  if (lane == 63) lds[wave] = x;
  __syncthreads();
  if (wave == 0) {
    int wv = (lane < 16) ? lds[lane] : 0;
#pragma unroll
    for (int off = 1; off < 16; off <<= 1) {
      int y = __shfl_up(wv, off);
      if (lane >= off) wv += y;
    }
    if (lane < 16) lds[lane] = wv;
  }
  __syncthreads();
  int wbase = (wave == 0) ? 0 : lds[wave - 1];
  *total = lds[15];
  __syncthreads();
  return wbase + x - v;
}

__device__ __forceinline__ void inv_diag3(const float* __restrict__ cell, float inv[9]) {
  float c[9];
#pragma unroll
  for (int i = 0; i < 9; i++) c[i] = cell[i];
  float a00=c[0],a01=c[1],a02=c[2],a10=c[3],a11=c[4],a12=c[5],a20=c[6],a21=c[7],a22=c[8];
  float m00 = __fsub_rn(__fmul_rn(a11,a22), __fmul_rn(a12,a21));
  float m01 = __fsub_rn(__fmul_rn(a10,a22), __fmul_rn(a12,a20));
  float m02 = __fsub_rn(__fmul_rn(a10,a21), __fmul_rn(a11,a20));
  float det = __fadd_rn(__fsub_rn(__fmul_rn(a00,m00), __fmul_rn(a01,m01)), __fmul_rn(a02,m02));
  inv[0] = __fdiv_rn(m00, det);
  inv[1] = __fdiv_rn(__fsub_rn(__fmul_rn(a02,a21), __fmul_rn(a01,a22)), det);
  inv[2] = __fdiv_rn(__fsub_rn(__fmul_rn(a01,a12), __fmul_rn(a02,a11)), det);
  inv[3] = __fdiv_rn(__fsub_rn(__fmul_rn(a12,a20), __fmul_rn(a10,a22)), det);
  inv[4] = __fdiv_rn(__fsub_rn(__fmul_rn(a00,a22), __fmul_rn(a02,a20)), det);
  inv[5] = __fdiv_rn(__fsub_rn(__fmul_rn(a02,a10), __fmul_rn(a00,a12)), det);
  inv[6] = __fdiv_rn(m02, det);
  inv[7] = __fdiv_rn(__fsub_rn(__fmul_rn(a01,a20), __fmul_rn(a00,a21)), det);
  inv[8] = __fdiv_rn(__fsub_rn(__fmul_rn(a00,a11), __fmul_rn(a01,a10)), det);
}

// per-axis image options; ascending p-component so combos enumerate in
// ascending stencil index p (reference stable-sort key order).
__device__ __forceinline__ int axis_opts(float w, float cdiag, int* pcomp, int* cellv,
                                         float* shv) {
  int cc = (int)floorf(__fdiv_rn(w, CUTOFF));
  int k = 0;
  if (cc >= 29) {
    float wp = __fsub_rn(w, cdiag);
    int c2 = (int)floorf(__fdiv_rn(wp, CUTOFF)) + 2;
    if ((unsigned)c2 < G) { pcomp[k] = 0; cellv[k] = c2; shv[k] = __fsub_rn(0.0f, cdiag); k++; }
  }
  pcomp[k] = 1; cellv[k] = cc + 2; shv[k] = 0.0f; k++;
  if (cc <= 2) {
    float wp = __fadd_rn(w, cdiag);
    int c2 = (int)floorf(__fdiv_rn(wp, CUTOFF)) + 2;
    if ((unsigned)c2 < G) { pcomp[k] = 2; cellv[k] = c2; shv[k] = cdiag; k++; }
  }
  return k;
}

// pair test (bit-exact reference math). NaN-poisoned (empty) slots return
// false automatically: d = NaN, NaN < CUTOFF is false.
__device__ __forceinline__ bool dist_ok(float4 f, float4 w) {
  float ax = __fsub_rn(f.x, w.x), ay = __fsub_rn(f.y, w.y), az = __fsub_rn(f.z, w.z);
  float d = __fsqrt_rn(__fadd_rn(__fadd_rn(__fmul_rn(ax, ax), __fmul_rn(ay, ay)),
                                 __fmul_rn(az, az)));
  return (d < CUTOFF && d > 0.01f);
}

// match mask for one (atom, cell) visit (fallback path; NaN slots filtered)
__device__ __forceinline__ unsigned match_mask(const float4* __restrict__ cdata,
                                               int base, int cnt, float4 w) {
  unsigned mask = 0;
  for (int q = 0; q < cnt; q++)
    if (dist_ok(cdata[base + q], w)) mask |= 1u << q;
  return mask;
}

// extract min-t bit from mask (entries are cache-hot 4B .w reads)
__device__ __forceinline__ int pick_min_t(const float4* __restrict__ cdata, int base,
                                          unsigned mask) {
  int bq = -1, bt = IMAX;
  for (unsigned m2 = mask; m2; m2 &= m2 - 1) {
    int q = __builtin_ctz(m2);
    int t = __float_as_int(cdata[base + q].w);
    if (t < bt) { bt = t; bq = q; }
  }
  return bq;
}

__device__ __forceinline__ void cswap(int& a, int& b) {
  int lo = min(a, b), hi = max(a, b);
  a = lo; b = hi;
}

__global__ void __launch_bounds__(NTHR)
k_fused(const float* __restrict__ pos, const float* __restrict__ cell,
        float* __restrict__ out, int n, int K,
        int* grp, int* top, int* rel, int* fill,
        float4* wrapped, int* pubSum, float4* cdata) {
  __shared__ int lds[32];
  __shared__ int pcache[NTHR * CSTR];    // 53 KB: pair slab-addresses, stride 13
  const int tid = threadIdx.x, blk = blockIdx.x;
  const int n27 = n * PIMG;

  // ---- P1: wrap + slab scatter, block-chunked (all 256 CUs share work) ----
  const int CH = (n + NBLK - 1) / NBLK;          // atoms per block (196)
  const int ai = blk * CH + tid;                 // coalesced within block
  if (tid < CH && ai < n) {
    float inv[9];
    inv_diag3(cell, inv);
    float px = pos[3*ai], py = pos[3*ai+1], pz = pos[3*ai+2];
    float m[3];
#pragma unroll
    for (int col = 0; col < 3; col++) {
      float s = __fadd_rn(__fadd_rn(__fmul_rn(px, inv[col]), __fmul_rn(py, inv[3+col])),
                          __fmul_rn(pz, inv[6+col]));
      s = __fadd_rn(s, WEPS);
      float t = __fsub_rn(s, floorf(s));
      m[col] = __fsub_rn(t, WEPS);
    }
    float wx = __fadd_rn(__fadd_rn(__fmul_rn(m[0], cell[0]), __fmul_rn(m[1], cell[3])),
                         __fmul_rn(m[2], cell[6]));
    float wy = __fadd_rn(__fadd_rn(__fmul_rn(m[0], cell[1]), __fmul_rn(m[1], cell[4])),
                         __fmul_rn(m[2], cell[7]));
    float wz = __fadd_rn(__fadd_rn(__fmul_rn(m[0], cell[2]), __fmul_rn(m[1], cell[5])),
                         __fmul_rn(m[2], cell[8]));
    wrapped[ai] = make_float4(wx, wy, wz, 0.0f);
    int px_[2], py_[2], pz_[2], cx_[2], cy_[2], cz_[2];
    float sx_[2], sy_[2], sz_[2];
    int nx = axis_opts(wx, cell[0], px_, cx_, sx_);
    int ny = axis_opts(wy, cell[4], py_, cy_, sy_);
    int nz = axis_opts(wz, cell[8], pz_, cz_, sz_);
    for (int a = 0; a < nx; a++)
      for (int b = 0; b < ny; b++)
        for (int c = 0; c < nz; c++) {
          int cid = (cx_[a] * G + cy_[b]) * G + cz_[c];
          int p = (px_[a] * 3 + py_[b]) * 3 + pz_[c];
          int slot = atomicAdd(&fill[cid], 1);
          if (slot < SLOT)
            cdata[cid * SLOT + slot] =
                make_float4(__fadd_rn(wx, sx_[a]), __fadd_rn(wy, sy_[b]),
                            __fadd_rn(wz, sz_[c]), __int_as_float(ai * PIMG + p));
        }
  }
  gsync(grp, top, rel, 1);   // the ONLY full barrier

  // ---- P2: pair count + LDS addr cache; fill-free NaN-filtered visits ----
  const int tbase = blk * PCH + tid * JPT;
  const int i0 = min(tbase, n27 - 1) / PIMG;
  const int i1 = min(tbase + JPT - 1, n27 - 1) / PIMG;
  const float4 w0 = wrapped[i0];                // independent loads
  const float4 w1 = wrapped[i1];
  const int cx0 = (int)floorf(__fdiv_rn(w0.x, CUTOFF)) + 2;
  const int cy0 = (int)floorf(__fdiv_rn(w0.y, CUTOFF)) + 2;
  const int cz0 = (int)floorf(__fdiv_rn(w0.z, CUTOFF)) + 2;
  const int cx1 = (int)floorf(__fdiv_rn(w1.x, CUTOFF)) + 2;
  const int cy1 = (int)floorf(__fdiv_rn(w1.y, CUTOFF)) + 2;
  const int cz1 = (int)floorf(__fdiv_rn(w1.z, CUTOFF)) + 2;
  int bases[JPT];                               // -1 == invalid (tail)
#pragma unroll
  for (int j = 0; j < JPT; j++) {               // pure ALU, no loads
    int idx = tbase + j;
    bool valid = idx < n27;
    int ic = valid ? idx / PIMG : i0;
    int s27 = valid ? idx - ic * PIMG : 0;
    bool a0 = (ic == i0);
    int dx = s27 / 9 - 1, dy = (s27 / 3) % 3 - 1, dz = s27 % 3 - 1;
    int cx = (a0 ? cx0 : cx1) + dx, cy = (a0 ? cy0 : cy1) + dy, cz = (a0 ? cz0 : cz1) + dz;
    int cid = (cx * G + cy) * G + cz;
    bases[j] = valid ? cid * SLOT : -1;
  }
  int tcnt = 0, c0 = 0;
#pragma unroll
  for (int j = 0; j < JPT; j++) {
    bool a0 = (tbase + j) < (i0 + 1) * PIMG;
    float4 w = a0 ? w0 : w1;
    int base = bases[j];
    int lbase = base < 0 ? 0 : base;            // clamp: loads unconditional
    // one 64B line per visit; empty slots are NaN -> dist_ok false
    float4 f0 = cdata[lbase + 0];
    float4 f1 = cdata[lbase + 1];
    float4 f2 = cdata[lbase + 2];
    float4 f3 = cdata[lbase + 3];
    if (base >= 0) {
      bool rare = false;
      if (__float_as_int(f3.w) >= 0) {          // slot3 occupied -> cnt >= 4 (~2%)
        int cnt = min(fill[base >> 4], SLOT);
        if (cnt > 4) {                          // true overflow path (<1%)
          rare = true;
          unsigned mask = match_mask(cdata, base, cnt, w);
          while (mask) {
            int bq = pick_min_t(cdata, base, mask);
            mask &= ~(1u << bq);
            if (tcnt < CAP) pcache[tid * CSTR + tcnt] = base + bq;
            tcnt++;
          }
        }
      }
      if (!rare) {
        // packed key t*16+q: preserves t order (t unique); IMAX = no match
        int a = dist_ok(f0, w) ? (__float_as_int(f0.w) * 16 + 0) : IMAX;
        int b = dist_ok(f1, w) ? (__float_as_int(f1.w) * 16 + 1) : IMAX;
        int c = dist_ok(f2, w) ? (__float_as_int(f2.w) * 16 + 2) : IMAX;
        int d = dist_ok(f3, w) ? (__float_as_int(f3.w) * 16 + 3) : IMAX;
        cswap(a, b); cswap(c, d); cswap(a, c); cswap(b, d); cswap(b, c);
        if (a != IMAX) { if (tcnt < CAP) pcache[tid * CSTR + tcnt] = base + (a & 15); tcnt++; }
        if (b != IMAX) { if (tcnt < CAP) pcache[tid * CSTR + tcnt] = base + (b & 15); tcnt++; }
        if (c != IMAX) { if (tcnt < CAP) pcache[tid * CSTR + tcnt] = base + (c & 15); tcnt++; }
        if (d != IMAX) { if (tcnt < CAP) pcache[tid * CSTR + tcnt] = base + (d & 15); tcnt++; }
      }
    }
    if (a0) c0 = tcnt;
  }
  int btotal;
  const int texcl = block_exscan(tcnt, lds, &btotal);   // register-carried offset

  // ---- fence-free all-gather of NBLK block sums (replaces barrier 2) ----
  // Only block sums cross blocks here; they travel through system-scope
  // atomics (coherent bypass). cdata/fill/wrapped were fenced at barrier 1 and
  // are unmodified since; pcache is per-block LDS. No memory fence needed ->
  // L2 stays hot into emit.
  if (tid == 0)
    __hip_atomic_store(&pubSum[blk], btotal + 1, __ATOMIC_RELAXED,
                       __HIP_MEMORY_SCOPE_SYSTEM);
  int v = 0;
  if (tid < NBLK) {
    int guard = 0;
    while ((v = __hip_atomic_load(&pubSum[tid], __ATOMIC_RELAXED,
                                  __HIP_MEMORY_SCOPE_SYSTEM)) == 0) {
      __builtin_amdgcn_s_sleep(2);
      if (++guard > SPINCAP) break;   // safety escape (wrong output, no hang)
    }
    v -= 1;
  }
  int obase, M;
  {
    int total;
    int ex = block_exscan(v, lds, &total);
    if (tid == blk) lds[16] = ex;       // this block's base (exactly one writer)
    if (tid == 0)   lds[17] = total;
    __syncthreads();
    obase = lds[16];
    M = lds[17];
  }

  // ---- P3: emit from LDS cache ----
  if (blk == 0 && tid == 0 && M != K) {
    float code = (M < K) ? (1000000.0f + (float)min(K - M, 100000))
                         : (2000000.0f + (float)min(M - K, 100000));
    for (int t = 0; t < 256; t++) out[t] = code;
  }
  int o = texcl + obase;
  if (tcnt <= CAP) {
    // fast path: K scattered reloads only (addresses cached in LDS; L2-hot)
    for (int k = 0; k < tcnt; k++) {
      float4 f = cdata[pcache[tid * CSTR + k]];
      bool a0 = (k < c0);
      float4 w = a0 ? w0 : w1;
      int i = a0 ? i0 : i1;
      float ax = __fsub_rn(f.x, w.x), ay = __fsub_rn(f.y, w.y), az = __fsub_rn(f.z, w.z);
      float d = __fsqrt_rn(__fadd_rn(__fadd_rn(__fmul_rn(ax, ax), __fmul_rn(ay, ay)),
                                     __fmul_rn(az, az)));
      if (o >= 0 && o < K) {
        int tt = __float_as_int(f.w);
        ((float2*)out)[o] = make_float2((float)i, (float)(tt / PIMG));
        size_t db = (size_t)2 * K + (size_t)3 * o;
        out[db]     = ax;
        out[db + 1] = ay;
        out[db + 2] = az;
        out[(size_t)5 * K + o] = d;
      }
      o++;
    }
  } else {
    // overflow fallback (P~1e-10): full re-traversal with same selection order
    // NaN-poisoned slots make cnt=SLOT safe (match_mask filters them).
#pragma unroll
    for (int j = 0; j < JPT; j++) {
      bool a0 = (tbase + j) < (i0 + 1) * PIMG;
      float4 w = a0 ? w0 : w1;
      int i = a0 ? i0 : i1;
      int base = bases[j];
      if (base < 0) continue;
      unsigned mask = match_mask(cdata, base, SLOT, w);
      while (mask) {
        int bq = pick_min_t(cdata, base, mask);
        mask &= ~(1u << bq);
        float4 f = cdata[base + bq];
        float ax = __fsub_rn(f.x, w.x), ay = __fsub_rn(f.y, w.y), az = __fsub_rn(f.z, w.z);
        float d = __fsqrt_rn(__fadd_rn(__fadd_rn(__fmul_rn(ax, ax), __fmul_rn(ay, ay)),
                                       __fmul_rn(az, az)));
        if (o >= 0 && o < K) {
          int tt = __float_as_int(f.w);
          ((float2*)out)[o] = make_float2((float)i, (float)(tt / PIMG));
          size_t db = (size_t)2 * K + (size_t)3 * o;
          out[db]     = ax;
          out[db + 1] = ay;
          out[db + 2] = az;
          out[(size_t)5 * K + o] = d;
        }
        o++;
      }
    }
  }
}

extern "C" void kernel_launch(void* const* d_in, const int* in_sizes, int n_in,
                              void* d_out, int out_size, void* d_ws, size_t ws_size,
                              hipStream_t stream) {
  const float* pos  = (const float*)d_in[0];
  const float* cell = (const float*)d_in[1];
  float* out = (float*)d_out;
  int n = in_sizes[0] / 3;
  int K = out_size / 6;

  char* ws = (char*)d_ws;
  size_t off = 0;
  auto alloc = [&](size_t bytes) -> char* {
    char* p = ws + off;
    off = (off + bytes + 255) & ~(size_t)255;
    return p;
  };
  // zeroed region first (single small memset): grp | top | rel | pubSum | fill
  int*    grp      = (int*)alloc((size_t)NGRP * GSTR * 4);   // 4 KB, 16 lines
  int*    top      = (int*)alloc(256);
  int*    rel      = (int*)alloc(256);
  int*    pubSum   = (int*)alloc((size_t)NBLK * 4);
  int*    fill     = (int*)alloc((size_t)NCELLS * 4);        // 187 KB
  size_t  zbytes   = off;
  float4* wrapped  = (float4*)alloc((size_t)n * 16);
  float4* cdata    = (float4*)alloc((size_t)NCELLS * SLOT * 16);   // 11.9 MB
  if (off > ws_size) return;

  (void)hipMemsetAsync(ws, 0, zbytes, stream);
  // NaN-poison cdata: 0xFFFFFFFF floats -> dist_ok false, t = -1 (empty marker)
  (void)hipMemsetAsync(cdata, 0xFF, (size_t)NCELLS * SLOT * 16, stream);
  k_fused<<<NBLK, NTHR, 0, stream>>>(pos, cell, out, n, K, grp, top, rel, fill,
                                     wrapped, pubSum, cdata);
}

// Round 3
// 122.061 us; speedup vs baseline: 1.1668x; 1.0838x over previous
//
#include <hip/hip_runtime.h>
#include <hip/hip_bf16.h>

// TorchNeighborList on MI355X. Output: FLOAT32, pairs[K,2] | diff[K,3] | dist[K].
// R19: geometric visit pruning on the proven R16 base (70.2us).
// R17 post-mortem: 2x occupancy -> 0 extra issue (per-CU scattered-request
// processing bound). R18 post-mortem: NaN-memset evicted cdata from L2/L3
// (FETCH +10MB, dur +3.4us) -- reverted; fill reads are L2-hot and cheap.
// The cost driver is the ~1.13M random cdata 64B line fetches in P2.
// New: per-visit box-distance prune. For neighbor cell c: per-axis
// v=max(lo-w, w-lo-5, 0); if vx^2+vy^2+vz^2 > 25+1e-3 the cell provably
// holds no pair (box dist lower-bounds every image dist; margin >> f32
// rounding) -> skip fill AND cdata loads. Expected visits 27 -> ~20.6 (-24%).
// Prune is output-invariant: skipped cells contribute nothing in the
// reference either; ordering machinery untouched.
// Ordering contract (passing since R3): atom i ascending -> 27-stencil
// cart3(1,1,1) row-major -> within cell t=i*27+p ascending.
// All f32 math for OUTPUT values via _rn intrinsics (no FMA contraction) to
// bit-match numpy/jax; prune math is ordinary f32 (gate only, margin-covered).

#define CUTOFF 5.0f
#define WEPS   1e-7f
#define PIMG   27
#define G      36
#define NCELLS (G*G*G)          // 46656
#define SLOT   16               // images per cell slab
#define NBLK   256
#define NTHR   1024
#define TOTT   (NBLK*NTHR)      // 262144
#define JPT    6                // consecutive (atom,stencil) idx per thread
#define PCH    (NTHR*JPT)       // 6144 idx per block
#define CAP    12               // cached pair addrs per thread
#define CSTR   13               // LDS stride (odd -> bank-conflict-free)
#define NGRP   16
#define BPG    (NBLK/NGRP)      // 16 blocks per barrier group
#define GSTR   64               // ints between group counters (256B lines)
#define IMAX   0x7FFFFFFF
#define SPINCAP (1<<20)         // bounded spin: fail visibly instead of hang
#define PRUNE2 25.001f          // CUTOFF^2 + margin (conservative keep)

// grid barrier (used ONCE, after P1): release-RMW arrival tree; spin on
// RELAXED system-scope load; one fence after exit.
// Safe: 256 blocks x 1 block/CU, all co-resident.
__device__ __forceinline__ void gsync(int* grp, int* top, int* rel, int phase) {
  __syncthreads();
  if (threadIdx.x == 0) {
    __threadfence();   // release
    int g = blockIdx.x & (NGRP - 1);
    if (__hip_atomic_fetch_add(&grp[g * GSTR], 1, __ATOMIC_RELEASE,
                               __HIP_MEMORY_SCOPE_AGENT) == BPG * phase - 1) {
      if (__hip_atomic_fetch_add(top, 1, __ATOMIC_RELEASE,
                                 __HIP_MEMORY_SCOPE_AGENT) == NGRP * phase - 1) {
        __hip_atomic_store(rel, phase, __ATOMIC_RELEASE, __HIP_MEMORY_SCOPE_SYSTEM);
      }
    }
    int guard = 0;
    while (__hip_atomic_load(rel, __ATOMIC_RELAXED, __HIP_MEMORY_SCOPE_SYSTEM) < phase) {
      __builtin_amdgcn_s_sleep(8);
      if (++guard > SPINCAP) break;   // safety escape (wrong output, no hang)
    }
    __threadfence();   // acquire
  }
  __syncthreads();
}

// block-wide exclusive scan over 1024 threads (16 waves). lds >= 18 ints.
__device__ __forceinline__ int block_exscan(int v, int* lds, int* total) {
  int tid = threadIdx.x, lane = tid & 63, wave = tid >> 6;
  int x = v;
#pragma unroll
  for (int off = 1; off < 64; off <<= 1) {
    int y = __shfl_up(x, off);
    if (lane >= off) x += y;
  }
  if (lane == 63) lds[wave] = x;
  __syncthreads();
  if (wave == 0) {
    int wv = (lane < 16) ? lds[lane] : 0;
#pragma unroll
    for (int off = 1; off < 16; off <<= 1) {
      int y = __shfl_up(wv, off);
      if (lane >= off) wv += y;
    }
    if (lane < 16) lds[lane] = wv;
  }
  __syncthreads();
  int wbase = (wave == 0) ? 0 : lds[wave - 1];
  *total = lds[15];
  __syncthreads();
  return wbase + x - v;
}

__device__ __forceinline__ void inv_diag3(const float* __restrict__ cell, float inv[9]) {
  float c[9];
#pragma unroll
  for (int i = 0; i < 9; i++) c[i] = cell[i];
  float a00=c[0],a01=c[1],a02=c[2],a10=c[3],a11=c[4],a12=c[5],a20=c[6],a21=c[7],a22=c[8];
  float m00 = __fsub_rn(__fmul_rn(a11,a22), __fmul_rn(a12,a21));
  float m01 = __fsub_rn(__fmul_rn(a10,a22), __fmul_rn(a12,a20));
  float m02 = __fsub_rn(__fmul_rn(a10,a21), __fmul_rn(a11,a20));
  float det = __fadd_rn(__fsub_rn(__fmul_rn(a00,m00), __fmul_rn(a01,m01)), __fmul_rn(a02,m02));
  inv[0] = __fdiv_rn(m00, det);
  inv[1] = __fdiv_rn(__fsub_rn(__fmul_rn(a02,a21), __fmul_rn(a01,a22)), det);
  inv[2] = __fdiv_rn(__fsub_rn(__fmul_rn(a01,a12), __fmul_rn(a02,a11)), det);
  inv[3] = __fdiv_rn(__fsub_rn(__fmul_rn(a12,a20), __fmul_rn(a10,a22)), det);
  inv[4] = __fdiv_rn(__fsub_rn(__fmul_rn(a00,a22), __fmul_rn(a02,a20)), det);
  inv[5] = __fdiv_rn(__fsub_rn(__fmul_rn(a02,a10), __fmul_rn(a00,a12)), det);
  inv[6] = __fdiv_rn(m02, det);
  inv[7] = __fdiv_rn(__fsub_rn(__fmul_rn(a01,a20), __fmul_rn(a00,a21)), det);
  inv[8] = __fdiv_rn(__fsub_rn(__fmul_rn(a00,a11), __fmul_rn(a01,a10)), det);
}

// per-axis image options; ascending p-component so combos enumerate in
// ascending stencil index p (reference stable-sort key order).
__device__ __forceinline__ int axis_opts(float w, float cdiag, int* pcomp, int* cellv,
                                         float* shv) {
  int cc = (int)floorf(__fdiv_rn(w, CUTOFF));
  int k = 0;
  if (cc >= 29) {
    float wp = __fsub_rn(w, cdiag);
    int c2 = (int)floorf(__fdiv_rn(wp, CUTOFF)) + 2;
    if ((unsigned)c2 < G) { pcomp[k] = 0; cellv[k] = c2; shv[k] = __fsub_rn(0.0f, cdiag); k++; }
  }
  pcomp[k] = 1; cellv[k] = cc + 2; shv[k] = 0.0f; k++;
  if (cc <= 2) {
    float wp = __fadd_rn(w, cdiag);
    int c2 = (int)floorf(__fdiv_rn(wp, CUTOFF)) + 2;
    if ((unsigned)c2 < G) { pcomp[k] = 2; cellv[k] = c2; shv[k] = cdiag; k++; }
  }
  return k;
}

// pair test (bit-exact reference math)
__device__ __forceinline__ bool dist_ok(float4 f, float4 w) {
  float ax = __fsub_rn(f.x, w.x), ay = __fsub_rn(f.y, w.y), az = __fsub_rn(f.z, w.z);
  float d = __fsqrt_rn(__fadd_rn(__fadd_rn(__fmul_rn(ax, ax), __fmul_rn(ay, ay)),
                                 __fmul_rn(az, az)));
  return (d < CUTOFF && d > 0.01f);
}

// match mask for one (atom, cell) visit (fallback path, cnt>4)
__device__ __forceinline__ unsigned match_mask(const float4* __restrict__ cdata,
                                               int base, int cnt, float4 w) {
  unsigned mask = 0;
  for (int q = 0; q < cnt; q++)
    if (dist_ok(cdata[base + q], w)) mask |= 1u << q;
  return mask;
}

// extract min-t bit from mask (entries are cache-hot 4B .w reads)
__device__ __forceinline__ int pick_min_t(const float4* __restrict__ cdata, int base,
                                          unsigned mask) {
  int bq = -1, bt = IMAX;
  for (unsigned m2 = mask; m2; m2 &= m2 - 1) {
    int q = __builtin_ctz(m2);
    int t = __float_as_int(cdata[base + q].w);
    if (t < bt) { bt = t; bq = q; }
  }
  return bq;
}

// squared lower bound on distance from point w (one axis) to cell c's box.
// lo = (c-2)*5 exact in f32; ordinary math (gate only, PRUNE2 margin covers).
__device__ __forceinline__ float axis_q(float w, int c) {
  float lo = (float)((c - 2) * 5);
  float t = w - lo;
  float v = fmaxf(fmaxf(-t, t - 5.0f), 0.0f);
  return v * v;
}

__device__ __forceinline__ void cswap(int& a, int& b) {
  int lo = min(a, b), hi = max(a, b);
  a = lo; b = hi;
}

__global__ void __launch_bounds__(NTHR)
k_fused(const float* __restrict__ pos, const float* __restrict__ cell,
        float* __restrict__ out, int n, int K,
        int* grp, int* top, int* rel, int* fill,
        float4* wrapped, int* pubSum, float4* cdata) {
  __shared__ int lds[32];
  __shared__ int pcache[NTHR * CSTR];    // 53 KB: pair slab-addresses, stride 13
  const int tid = threadIdx.x, blk = blockIdx.x;
  const int n27 = n * PIMG;

  // ---- P1: wrap + slab scatter, block-chunked (all 256 CUs share work) ----
  const int CH = (n + NBLK - 1) / NBLK;          // atoms per block (196)
  const int ai = blk * CH + tid;                 // coalesced within block
  if (tid < CH && ai < n) {
    float inv[9];
    inv_diag3(cell, inv);
    float px = pos[3*ai], py = pos[3*ai+1], pz = pos[3*ai+2];
    float m[3];
#pragma unroll
    for (int col = 0; col < 3; col++) {
      float s = __fadd_rn(__fadd_rn(__fmul_rn(px, inv[col]), __fmul_rn(py, inv[3+col])),
                          __fmul_rn(pz, inv[6+col]));
      s = __fadd_rn(s, WEPS);
      float t = __fsub_rn(s, floorf(s));
      m[col] = __fsub_rn(t, WEPS);
    }
    float wx = __fadd_rn(__fadd_rn(__fmul_rn(m[0], cell[0]), __fmul_rn(m[1], cell[3])),
                         __fmul_rn(m[2], cell[6]));
    float wy = __fadd_rn(__fadd_rn(__fmul_rn(m[0], cell[1]), __fmul_rn(m[1], cell[4])),
                         __fmul_rn(m[2], cell[7]));
    float wz = __fadd_rn(__fadd_rn(__fmul_rn(m[0], cell[2]), __fmul_rn(m[1], cell[5])),
                         __fmul_rn(m[2], cell[8]));
    wrapped[ai] = make_float4(wx, wy, wz, 0.0f);
    int px_[2], py_[2], pz_[2], cx_[2], cy_[2], cz_[2];
    float sx_[2], sy_[2], sz_[2];
    int nx = axis_opts(wx, cell[0], px_, cx_, sx_);
    int ny = axis_opts(wy, cell[4], py_, cy_, sy_);
    int nz = axis_opts(wz, cell[8], pz_, cz_, sz_);
    for (int a = 0; a < nx; a++)
      for (int b = 0; b < ny; b++)
        for (int c = 0; c < nz; c++) {
          int cid = (cx_[a] * G + cy_[b]) * G + cz_[c];
          int p = (px_[a] * 3 + py_[b]) * 3 + pz_[c];
          int slot = atomicAdd(&fill[cid], 1);
          if (slot < SLOT)
            cdata[cid * SLOT + slot] =
                make_float4(__fadd_rn(wx, sx_[a]), __fadd_rn(wy, sy_[b]),
                            __fadd_rn(wz, sz_[c]), __int_as_float(ai * PIMG + p));
        }
  }
  gsync(grp, top, rel, 1);   // the ONLY full barrier

  // ---- P2: pair count + LDS addr cache; box-pruned, fill-gated visits ----
  const int tbase = blk * PCH + tid * JPT;
  const int i0 = min(tbase, n27 - 1) / PIMG;
  const int i1 = min(tbase + JPT - 1, n27 - 1) / PIMG;
  const float4 w0 = wrapped[i0];                // independent loads
  const float4 w1 = wrapped[i1];
  const int cx0 = (int)floorf(__fdiv_rn(w0.x, CUTOFF)) + 2;
  const int cy0 = (int)floorf(__fdiv_rn(w0.y, CUTOFF)) + 2;
  const int cz0 = (int)floorf(__fdiv_rn(w0.z, CUTOFF)) + 2;
  const int cx1 = (int)floorf(__fdiv_rn(w1.x, CUTOFF)) + 2;
  const int cy1 = (int)floorf(__fdiv_rn(w1.y, CUTOFF)) + 2;
  const int cz1 = (int)floorf(__fdiv_rn(w1.z, CUTOFF)) + 2;
  int bases[JPT], cnts[JPT];
#pragma unroll
  for (int j = 0; j < JPT; j++) {               // prune + independent fill loads
    int idx = tbase + j;
    bool valid = idx < n27;
    int ic = valid ? idx / PIMG : i0;
    int s27 = valid ? idx - ic * PIMG : 0;
    bool a0 = (ic == i0);
    int ix = s27 / 9, iy = (s27 / 3) % 3, iz = s27 % 3;
    float wxs = a0 ? w0.x : w1.x, wys = a0 ? w0.y : w1.y, wzs = a0 ? w0.z : w1.z;
    int cx = (a0 ? cx0 : cx1) + ix - 1;
    int cy = (a0 ? cy0 : cy1) + iy - 1;
    int cz = (a0 ? cz0 : cz1) + iz - 1;
    // box lower-bound distance^2 to this neighbor cell; > 25+eps -> no pair
    float ps = axis_q(wxs, cx) + axis_q(wys, cy) + axis_q(wzs, cz);
    bool keep = valid && (ps <= PRUNE2);
    int cid = (cx * G + cy) * G + cz;
    bases[j] = cid * SLOT;
    cnts[j] = keep ? min(fill[cid], SLOT) : 0;
  }
  int tcnt = 0, c0 = 0;
#pragma unroll
  for (int j = 0; j < JPT; j++) {
    bool a0 = (tbase + j) < (i0 + 1) * PIMG;
    float4 w = a0 ? w0 : w1;
    int base = bases[j], cnt = cnts[j];
    if (cnt > 0) {
      if (cnt <= 4) {
        // common path: 4 unconditional independent loads from the
        // 64B-aligned slab head (over-read is same-line; garbage masked).
        float4 f0 = cdata[base + 0];
        float4 f1 = cdata[base + 1];
        float4 f2 = cdata[base + 2];
        float4 f3 = cdata[base + 3];
        // packed key t*16+q: preserves t order (t unique); IMAX = no match
        int a = (cnt > 0 && dist_ok(f0, w)) ? (__float_as_int(f0.w) * 16 + 0) : IMAX;
        int b = (cnt > 1 && dist_ok(f1, w)) ? (__float_as_int(f1.w) * 16 + 1) : IMAX;
        int c = (cnt > 2 && dist_ok(f2, w)) ? (__float_as_int(f2.w) * 16 + 2) : IMAX;
        int d = (cnt > 3 && dist_ok(f3, w)) ? (__float_as_int(f3.w) * 16 + 3) : IMAX;
        cswap(a, b); cswap(c, d); cswap(a, c); cswap(b, d); cswap(b, c);
        if (a != IMAX) { if (tcnt < CAP) pcache[tid * CSTR + tcnt] = base + (a & 15); tcnt++; }
        if (b != IMAX) { if (tcnt < CAP) pcache[tid * CSTR + tcnt] = base + (b & 15); tcnt++; }
        if (c != IMAX) { if (tcnt < CAP) pcache[tid * CSTR + tcnt] = base + (c & 15); tcnt++; }
        if (d != IMAX) { if (tcnt < CAP) pcache[tid * CSTR + tcnt] = base + (d & 15); tcnt++; }
      } else {
        // rare path (~2%): scalar loop + min-t selection (R11 exact)
        unsigned mask = match_mask(cdata, base, cnt, w);
        while (mask) {
          int bq = pick_min_t(cdata, base, mask);
          mask &= ~(1u << bq);
          if (tcnt < CAP) pcache[tid * CSTR + tcnt] = base + bq;
          tcnt++;
        }
      }
    }
    if (a0) c0 = tcnt;
  }
  int btotal;
  const int texcl = block_exscan(tcnt, lds, &btotal);   // register-carried offset

  // ---- fence-free all-gather of NBLK block sums (replaces barrier 2) ----
  // Only block sums cross blocks here; they travel through system-scope
  // atomics (coherent bypass). cdata/fill/wrapped were fenced at barrier 1 and
  // are unmodified since; pcache is per-block LDS. No memory fence needed ->
  // L2 stays hot into emit.
  if (tid == 0)
    __hip_atomic_store(&pubSum[blk], btotal + 1, __ATOMIC_RELAXED,
                       __HIP_MEMORY_SCOPE_SYSTEM);
  int v = 0;
  if (tid < NBLK) {
    int guard = 0;
    while ((v = __hip_atomic_load(&pubSum[tid], __ATOMIC_RELAXED,
                                  __HIP_MEMORY_SCOPE_SYSTEM)) == 0) {
      __builtin_amdgcn_s_sleep(2);
      if (++guard > SPINCAP) break;   // safety escape (wrong output, no hang)
    }
    v -= 1;
  }
  int obase, M;
  {
    int total;
    int ex = block_exscan(v, lds, &total);
    if (tid == blk) lds[16] = ex;       // this block's base (exactly one writer)
    if (tid == 0)   lds[17] = total;
    __syncthreads();
    obase = lds[16];
    M = lds[17];
  }

  // ---- P3: emit from LDS cache ----
  if (blk == 0 && tid == 0 && M != K) {
    float code = (M < K) ? (1000000.0f + (float)min(K - M, 100000))
                         : (2000000.0f + (float)min(M - K, 100000));
    for (int t = 0; t < 256; t++) out[t] = code;
  }
  int o = texcl + obase;
  if (tcnt <= CAP) {
    // fast path: K scattered reloads only (addresses cached in LDS; L2-hot)
    for (int k = 0; k < tcnt; k++) {
      float4 f = cdata[pcache[tid * CSTR + k]];
      bool a0 = (k < c0);
      float4 w = a0 ? w0 : w1;
      int i = a0 ? i0 : i1;
      float ax = __fsub_rn(f.x, w.x), ay = __fsub_rn(f.y, w.y), az = __fsub_rn(f.z, w.z);
      float d = __fsqrt_rn(__fadd_rn(__fadd_rn(__fmul_rn(ax, ax), __fmul_rn(ay, ay)),
                                     __fmul_rn(az, az)));
      if (o >= 0 && o < K) {
        int tt = __float_as_int(f.w);
        ((float2*)out)[o] = make_float2((float)i, (float)(tt / PIMG));
        size_t db = (size_t)2 * K + (size_t)3 * o;
        out[db]     = ax;
        out[db + 1] = ay;
        out[db + 2] = az;
        out[(size_t)5 * K + o] = d;
      }
      o++;
    }
  } else {
    // overflow fallback (P~1e-10): full re-traversal with same selection order
#pragma unroll
    for (int j = 0; j < JPT; j++) {
      bool a0 = (tbase + j) < (i0 + 1) * PIMG;
      float4 w = a0 ? w0 : w1;
      int i = a0 ? i0 : i1;
      int base = bases[j];
      unsigned mask = match_mask(cdata, base, cnts[j], w);
      while (mask) {
        int bq = pick_min_t(cdata, base, mask);
        mask &= ~(1u << bq);
        float4 f = cdata[base + bq];
        float ax = __fsub_rn(f.x, w.x), ay = __fsub_rn(f.y, w.y), az = __fsub_rn(f.z, w.z);
        float d = __fsqrt_rn(__fadd_rn(__fadd_rn(__fmul_rn(ax, ax), __fmul_rn(ay, ay)),
                                       __fmul_rn(az, az)));
        if (o >= 0 && o < K) {
          int tt = __float_as_int(f.w);
          ((float2*)out)[o] = make_float2((float)i, (float)(tt / PIMG));
          size_t db = (size_t)2 * K + (size_t)3 * o;
          out[db]     = ax;
          out[db + 1] = ay;
          out[db + 2] = az;
          out[(size_t)5 * K + o] = d;
        }
        o++;
      }
    }
  }
}

extern "C" void kernel_launch(void* const* d_in, const int* in_sizes, int n_in,
                              void* d_out, int out_size, void* d_ws, size_t ws_size,
                              hipStream_t stream) {
  const float* pos  = (const float*)d_in[0];
  const float* cell = (const float*)d_in[1];
  float* out = (float*)d_out;
  int n = in_sizes[0] / 3;
  int K = out_size / 6;

  char* ws = (char*)d_ws;
  size_t off = 0;
  auto alloc = [&](size_t bytes) -> char* {
    char* p = ws + off;
    off = (off + bytes + 255) & ~(size_t)255;
    return p;
  };
  // zeroed region first (single small memset): grp | top | rel | pubSum | fill
  int*    grp      = (int*)alloc((size_t)NGRP * GSTR * 4);   // 4 KB, 16 lines
  int*    top      = (int*)alloc(256);
  int*    rel      = (int*)alloc(256);
  int*    pubSum   = (int*)alloc((size_t)NBLK * 4);
  int*    fill     = (int*)alloc((size_t)NCELLS * 4);        // 187 KB
  size_t  zbytes   = off;
  float4* wrapped  = (float4*)alloc((size_t)n * 16);
  float4* cdata    = (float4*)alloc((size_t)NCELLS * SLOT * 16);   // 11.9 MB
  if (off > ws_size) return;

  (void)hipMemsetAsync(ws, 0, zbytes, stream);
  k_fused<<<NBLK, NTHR, 0, stream>>>(pos, cell, out, n, K, grp, top, rel, fill,
                                     wrapped, pubSum, cdata);
}

// Round 5
// 99.093 us; speedup vs baseline: 1.4373x; 1.2318x over previous
//
#include <hip/hip_runtime.h>

// TorchNeighborList on MI355X. Output: FLOAT32, pairs[K,2] | diff[K,3] | dist[K].
// R21: kernel split. R20 post-mortem: fused design's grid barrier requires ALL
// blocks co-resident; natural VGPR drifted >64 -> 1 block/CU -> barrier could
// not complete -> guard escape -> garbage. Correctness was coupled to
// occupancy. Fix: split at the barrier points into 4 stream-serialized
// kernels (build -> pair -> scan -> emit). Stream order is the fence: no
// gsync, no pubSum all-gather, no co-residency cliff, and each phase runs at
// its own best occupancy (k_pair: 2048x256, natural VGPR, up to 32 waves/CU).
// Pair addrs flow pair->emit via global scratch int2(slab addr, center atom)
// (8.4 MB). Thread overflow (tcnt>CAP): exact in-kernel re-traversal while
// bases[]/cnts[] still live. Block overflow (>BCAP): writes clamped but TRUE
// sum reported -> M != K -> loud fail (P~0). Bonus: rocprof now shows
// per-phase dur_us -- ends blind phase attribution.
// Keeps R19's box prune (proven -2.5us) and R16's visit/selection machinery.
// Ordering contract: block-ascending (scan of block sums) -> thread-ascending
// (block exscan) -> within-thread j ascending, min-t within cell. Identical
// to reference stable-sort order (passing since R3).
// All OUTPUT math via _rn intrinsics (no FMA contraction) to bit-match
// numpy/jax; prune math ordinary f32 (gate only, margin-covered).

#define CUTOFF 5.0f
#define WEPS   1e-7f
#define PIMG   27
#define G      36
#define NCELLS (G*G*G)          // 46656
#define SLOT   16               // images per cell slab
#define NT1    256              // k_build block size
#define NB2    2048             // k_pair/k_emit grid
#define NT2    256              // k_pair/k_emit block size
#define JPT    3                // (atom,stencil) idx per thread; 2048*256*3 >= n*27
#define CAP    16               // cached pair addrs per thread
#define CSTR   17               // LDS stride (odd -> bank-conflict-free)
#define BCAP   512              // per-block pair capacity (expect ~182, 2.8x headroom)
#define IMAX   0x7FFFFFFF
#define PRUNE2 25.001f          // CUTOFF^2 + margin (conservative keep)

// ---------- shared helpers ----------

__device__ __forceinline__ void inv_diag3(const float* __restrict__ cell, float inv[9]) {
  float c[9];
#pragma unroll
  for (int i = 0; i < 9; i++) c[i] = cell[i];
  float a00=c[0],a01=c[1],a02=c[2],a10=c[3],a11=c[4],a12=c[5],a20=c[6],a21=c[7],a22=c[8];
  float m00 = __fsub_rn(__fmul_rn(a11,a22), __fmul_rn(a12,a21));
  float m01 = __fsub_rn(__fmul_rn(a10,a22), __fmul_rn(a12,a20));
  float m02 = __fsub_rn(__fmul_rn(a10,a21), __fmul_rn(a11,a20));
  float det = __fadd_rn(__fsub_rn(__fmul_rn(a00,m00), __fmul_rn(a01,m01)), __fmul_rn(a02,m02));
  inv[0] = __fdiv_rn(m00, det);
  inv[1] = __fdiv_rn(__fsub_rn(__fmul_rn(a02,a21), __fmul_rn(a01,a22)), det);
  inv[2] = __fdiv_rn(__fsub_rn(__fmul_rn(a01,a12), __fmul_rn(a02,a11)), det);
  inv[3] = __fdiv_rn(__fsub_rn(__fmul_rn(a12,a20), __fmul_rn(a10,a22)), det);
  inv[4] = __fdiv_rn(__fsub_rn(__fmul_rn(a00,a22), __fmul_rn(a02,a20)), det);
  inv[5] = __fdiv_rn(__fsub_rn(__fmul_rn(a02,a10), __fmul_rn(a00,a12)), det);
  inv[6] = __fdiv_rn(m02, det);
  inv[7] = __fdiv_rn(__fsub_rn(__fmul_rn(a01,a20), __fmul_rn(a00,a21)), det);
  inv[8] = __fdiv_rn(__fsub_rn(__fmul_rn(a00,a11), __fmul_rn(a01,a10)), det);
}

// per-axis image options; ascending p-component (reference stable-sort order).
__device__ __forceinline__ int axis_opts(float w, float cdiag, int* pcomp, int* cellv,
                                         float* shv) {
  int cc = (int)floorf(__fdiv_rn(w, CUTOFF));
  int k = 0;
  if (cc >= 29) {
    float wp = __fsub_rn(w, cdiag);
    int c2 = (int)floorf(__fdiv_rn(wp, CUTOFF)) + 2;
    if ((unsigned)c2 < G) { pcomp[k] = 0; cellv[k] = c2; shv[k] = __fsub_rn(0.0f, cdiag); k++; }
  }
  pcomp[k] = 1; cellv[k] = cc + 2; shv[k] = 0.0f; k++;
  if (cc <= 2) {
    float wp = __fadd_rn(w, cdiag);
    int c2 = (int)floorf(__fdiv_rn(wp, CUTOFF)) + 2;
    if ((unsigned)c2 < G) { pcomp[k] = 2; cellv[k] = c2; shv[k] = cdiag; k++; }
  }
  return k;
}

// pair test (bit-exact reference math)
__device__ __forceinline__ bool dist_ok(float4 f, float4 w) {
  float ax = __fsub_rn(f.x, w.x), ay = __fsub_rn(f.y, w.y), az = __fsub_rn(f.z, w.z);
  float d = __fsqrt_rn(__fadd_rn(__fadd_rn(__fmul_rn(ax, ax), __fmul_rn(ay, ay)),
                                 __fmul_rn(az, az)));
  return (d < CUTOFF && d > 0.01f);
}

__device__ __forceinline__ unsigned match_mask(const float4* __restrict__ cdata,
                                               int base, int cnt, float4 w) {
  unsigned mask = 0;
  for (int q = 0; q < cnt; q++)
    if (dist_ok(cdata[base + q], w)) mask |= 1u << q;
  return mask;
}

__device__ __forceinline__ int pick_min_t(const float4* __restrict__ cdata, int base,
                                          unsigned mask) {
  int bq = -1, bt = IMAX;
  for (unsigned m2 = mask; m2; m2 &= m2 - 1) {
    int q = __builtin_ctz(m2);
    int t = __float_as_int(cdata[base + q].w);
    if (t < bt) { bt = t; bq = q; }
  }
  return bq;
}

// squared lower bound on distance from point w (one axis) to cell c's box.
__device__ __forceinline__ float axis_q(float w, int c) {
  float lo = (float)((c - 2) * 5);
  float t = w - lo;
  float v = fmaxf(fmaxf(-t, t - 5.0f), 0.0f);
  return v * v;
}

__device__ __forceinline__ void cswap(int& a, int& b) {
  int lo = min(a, b), hi = max(a, b);
  a = lo; b = hi;
}

// exclusive scan over 256 threads (4 waves). lds >= 8 ints.
__device__ __forceinline__ int exscan256(int v, int* lds, int* total) {
  int tid = threadIdx.x, lane = tid & 63, wave = tid >> 6;
  int x = v;
#pragma unroll
  for (int off = 1; off < 64; off <<= 1) {
    int y = __shfl_up(x, off);
    if (lane >= off) x += y;
  }
  if (lane == 63) lds[wave] = x;
  __syncthreads();
  if (wave == 0) {
    int wv = (lane < 4) ? lds[lane] : 0;
#pragma unroll
    for (int off = 1; off < 4; off <<= 1) {
      int y = __shfl_up(wv, off);
      if (lane >= off) wv += y;
    }
    if (lane < 4) lds[lane] = wv;
  }
  __syncthreads();
  int wbase = (wave == 0) ? 0 : lds[wave - 1];
  *total = lds[3];
  __syncthreads();
  return wbase + x - v;
}

// exclusive scan over 1024 threads (16 waves). lds >= 18 ints.
__device__ __forceinline__ int exscan1024(int v, int* lds, int* total) {
  int tid = threadIdx.x, lane = tid & 63, wave = tid >> 6;
  int x = v;
#pragma unroll
  for (int off = 1; off < 64; off <<= 1) {
    int y = __shfl_up(x, off);
    if (lane >= off) x += y;
  }
  if (lane == 63) lds[wave] = x;
  __syncthreads();
  if (wave == 0) {
    int wv = (lane < 16) ? lds[lane] : 0;
#pragma unroll
    for (int off = 1; off < 16; off <<= 1) {
      int y = __shfl_up(wv, off);
      if (lane >= off) wv += y;
    }
    if (lane < 16) lds[lane] = wv;
  }
  __syncthreads();
  int wbase = (wave == 0) ? 0 : lds[wave - 1];
  *total = lds[15];
  __syncthreads();
  return wbase + x - v;
}

// ---------- k_build: wrap atoms + scatter periodic images into cell slabs ----------
__global__ void __launch_bounds__(NT1)
k_build(const float* __restrict__ pos, const float* __restrict__ cell,
        int* __restrict__ fill, float4* __restrict__ wrapped,
        float4* __restrict__ cdata, int n) {
  const int ai = blockIdx.x * NT1 + threadIdx.x;
  if (ai >= n) return;
  float inv[9];
  inv_diag3(cell, inv);
  float px = pos[3*ai], py = pos[3*ai+1], pz = pos[3*ai+2];
  float m[3];
#pragma unroll
  for (int col = 0; col < 3; col++) {
    float s = __fadd_rn(__fadd_rn(__fmul_rn(px, inv[col]), __fmul_rn(py, inv[3+col])),
                        __fmul_rn(pz, inv[6+col]));
    s = __fadd_rn(s, WEPS);
    float t = __fsub_rn(s, floorf(s));
    m[col] = __fsub_rn(t, WEPS);
  }
  float wx = __fadd_rn(__fadd_rn(__fmul_rn(m[0], cell[0]), __fmul_rn(m[1], cell[3])),
                       __fmul_rn(m[2], cell[6]));
  float wy = __fadd_rn(__fadd_rn(__fmul_rn(m[0], cell[1]), __fmul_rn(m[1], cell[4])),
                       __fmul_rn(m[2], cell[7]));
  float wz = __fadd_rn(__fadd_rn(__fmul_rn(m[0], cell[2]), __fmul_rn(m[1], cell[5])),
                       __fmul_rn(m[2], cell[8]));
  wrapped[ai] = make_float4(wx, wy, wz, 0.0f);
  int px_[2], py_[2], pz_[2], cx_[2], cy_[2], cz_[2];
  float sx_[2], sy_[2], sz_[2];
  int nx = axis_opts(wx, cell[0], px_, cx_, sx_);
  int ny = axis_opts(wy, cell[4], py_, cy_, sy_);
  int nz = axis_opts(wz, cell[8], pz_, cz_, sz_);
  for (int a = 0; a < nx; a++)
    for (int b = 0; b < ny; b++)
      for (int c = 0; c < nz; c++) {
        int cid = (cx_[a] * G + cy_[b]) * G + cz_[c];
        int p = (px_[a] * 3 + py_[b]) * 3 + pz_[c];
        int slot = atomicAdd(&fill[cid], 1);
        if (slot < SLOT)
          cdata[cid * SLOT + slot] =
              make_float4(__fadd_rn(wx, sx_[a]), __fadd_rn(wy, sy_[b]),
                          __fadd_rn(wz, sz_[c]), __int_as_float(ai * PIMG + p));
      }
}

// ---------- k_pair: box-pruned visits -> compacted (addr, center) runs ----------
__global__ void __launch_bounds__(NT2)
k_pair(const float4* __restrict__ wrapped, const int* __restrict__ fill,
       const float4* __restrict__ cdata, int2* __restrict__ paddr,
       int* __restrict__ blockSum, int n) {
  __shared__ int lds[8];
  __shared__ int pcache[NT2 * CSTR];     // 17.4 KB
  const int tid = threadIdx.x, blk = blockIdx.x;
  const int n27 = n * PIMG;
  const int tbase = (blk * NT2 + tid) * JPT;
  const int i0 = min(tbase, n27 - 1) / PIMG;
  const int i1 = min(tbase + JPT - 1, n27 - 1) / PIMG;
  const float4 w0 = wrapped[i0];
  const float4 w1 = wrapped[i1];
  const int cx0 = (int)floorf(__fdiv_rn(w0.x, CUTOFF)) + 2;
  const int cy0 = (int)floorf(__fdiv_rn(w0.y, CUTOFF)) + 2;
  const int cz0 = (int)floorf(__fdiv_rn(w0.z, CUTOFF)) + 2;
  const int cx1 = (int)floorf(__fdiv_rn(w1.x, CUTOFF)) + 2;
  const int cy1 = (int)floorf(__fdiv_rn(w1.y, CUTOFF)) + 2;
  const int cz1 = (int)floorf(__fdiv_rn(w1.z, CUTOFF)) + 2;
  int bases[JPT], cnts[JPT];
#pragma unroll
  for (int j = 0; j < JPT; j++) {        // prune + independent fill loads
    int idx = tbase + j;
    bool valid = idx < n27;
    int ic = valid ? idx / PIMG : i0;
    int s27 = valid ? idx - ic * PIMG : 0;
    bool a0 = (ic == i0);
    int ix = s27 / 9, iy = (s27 / 3) % 3, iz = s27 % 3;
    float wxs = a0 ? w0.x : w1.x, wys = a0 ? w0.y : w1.y, wzs = a0 ? w0.z : w1.z;
    int cx = (a0 ? cx0 : cx1) + ix - 1;
    int cy = (a0 ? cy0 : cy1) + iy - 1;
    int cz = (a0 ? cz0 : cz1) + iz - 1;
    float ps = axis_q(wxs, cx) + axis_q(wys, cy) + axis_q(wzs, cz);
    bool keep = valid && (ps <= PRUNE2);
    int cid = (cx * G + cy) * G + cz;
    bases[j] = cid * SLOT;
    cnts[j] = keep ? min(fill[cid], SLOT) : 0;
  }
  int tcnt = 0, c0 = 0;
#pragma unroll
  for (int j = 0; j < JPT; j++) {
    bool a0 = (tbase + j) < (i0 + 1) * PIMG;
    float4 w = a0 ? w0 : w1;
    int base = bases[j], cnt = cnts[j];
    if (cnt > 0) {
      if (cnt <= 4) {
        // common path: 4 unconditional loads from the 64B-aligned slab head
        float4 f0 = cdata[base + 0];
        float4 f1 = cdata[base + 1];
        float4 f2 = cdata[base + 2];
        float4 f3 = cdata[base + 3];
        // packed key t*16+q preserves t order (t unique); IMAX = no match
        int a = (cnt > 0 && dist_ok(f0, w)) ? (__float_as_int(f0.w) * 16 + 0) : IMAX;
        int b = (cnt > 1 && dist_ok(f1, w)) ? (__float_as_int(f1.w) * 16 + 1) : IMAX;
        int c = (cnt > 2 && dist_ok(f2, w)) ? (__float_as_int(f2.w) * 16 + 2) : IMAX;
        int d = (cnt > 3 && dist_ok(f3, w)) ? (__float_as_int(f3.w) * 16 + 3) : IMAX;
        cswap(a, b); cswap(c, d); cswap(a, c); cswap(b, d); cswap(b, c);
        if (a != IMAX) { if (tcnt < CAP) pcache[tid * CSTR + tcnt] = base + (a & 15); tcnt++; }
        if (b != IMAX) { if (tcnt < CAP) pcache[tid * CSTR + tcnt] = base + (b & 15); tcnt++; }
        if (c != IMAX) { if (tcnt < CAP) pcache[tid * CSTR + tcnt] = base + (c & 15); tcnt++; }
        if (d != IMAX) { if (tcnt < CAP) pcache[tid * CSTR + tcnt] = base + (d & 15); tcnt++; }
      } else {
        // rare path (~2%): scalar loop + min-t selection
        unsigned mask = match_mask(cdata, base, cnt, w);
        while (mask) {
          int bq = pick_min_t(cdata, base, mask);
          mask &= ~(1u << bq);
          if (tcnt < CAP) pcache[tid * CSTR + tcnt] = base + bq;
          tcnt++;
        }
      }
    }
    if (a0) c0 = tcnt;
  }
  int btotal;
  const int texcl = exscan256(tcnt, lds, &btotal);
  if (tid == 0) blockSum[blk] = btotal;   // TRUE total (uncapped) -> loud fail on clamp
  int2* dst = paddr + (size_t)blk * BCAP;
  if (tcnt <= CAP) {
    for (int k = 0; k < tcnt; k++) {
      int o = texcl + k;
      if (o < BCAP) dst[o] = make_int2(pcache[tid * CSTR + k], (k < c0) ? i0 : i1);
    }
  } else {
    // exact overflow path (P~1e-9): re-traverse with same selection order;
    // bases/cnts still live in registers.
    int o = texcl;
#pragma unroll
    for (int j = 0; j < JPT; j++) {
      bool a0 = (tbase + j) < (i0 + 1) * PIMG;
      float4 w = a0 ? w0 : w1;
      int i = a0 ? i0 : i1;
      int base = bases[j];
      unsigned mask = match_mask(cdata, base, cnts[j], w);
      while (mask) {
        int bq = pick_min_t(cdata, base, mask);
        mask &= ~(1u << bq);
        if (o < BCAP) dst[o] = make_int2(base + bq, i);
        o++;
      }
    }
  }
}

// ---------- k_scan: ordered exscan of 2048 block sums ----------
__global__ void __launch_bounds__(1024)
k_scan(const int* __restrict__ blockSum, int* __restrict__ blockBase,
       float* __restrict__ out, int K) {
  __shared__ int lds[32];
  const int tid = threadIdx.x;
  int s0 = blockSum[2 * tid], s1 = blockSum[2 * tid + 1];
  int total;
  int ex = exscan1024(s0 + s1, lds, &total);
  blockBase[2 * tid] = ex;
  blockBase[2 * tid + 1] = ex + s0;
  if (tid == 0 && total != K) {
    float code = (total < K) ? (1000000.0f + (float)min(K - total, 100000))
                             : (2000000.0f + (float)min(total - K, 100000));
    for (int t = 0; t < 256; t++) out[t] = code;
  }
}

// ---------- k_emit: copy runs to final output with bit-exact math ----------
__global__ void __launch_bounds__(NT2)
k_emit(const float4* __restrict__ wrapped, const float4* __restrict__ cdata,
       const int2* __restrict__ paddr, const int* __restrict__ blockSum,
       const int* __restrict__ blockBase, float* __restrict__ out, int K) {
  const int blk = blockIdx.x;
  const int bs = min(blockSum[blk], BCAP);
  const int base = blockBase[blk];
  const int2* src = paddr + (size_t)blk * BCAP;
  for (int l = threadIdx.x; l < bs; l += NT2) {
    int2 e = src[l];
    float4 f = cdata[e.x];
    float4 w = wrapped[e.y];
    int o = base + l;
    float ax = __fsub_rn(f.x, w.x), ay = __fsub_rn(f.y, w.y), az = __fsub_rn(f.z, w.z);
    float d = __fsqrt_rn(__fadd_rn(__fadd_rn(__fmul_rn(ax, ax), __fmul_rn(ay, ay)),
                                   __fmul_rn(az, az)));
    if (o >= 0 && o < K) {
      int tt = __float_as_int(f.w);
      ((float2*)out)[o] = make_float2((float)e.y, (float)(tt / PIMG));
      size_t db = (size_t)2 * K + (size_t)3 * o;
      out[db]     = ax;
      out[db + 1] = ay;
      out[db + 2] = az;
      out[(size_t)5 * K + o] = d;
    }
  }
}

extern "C" void kernel_launch(void* const* d_in, const int* in_sizes, int n_in,
                              void* d_out, int out_size, void* d_ws, size_t ws_size,
                              hipStream_t stream) {
  const float* pos  = (const float*)d_in[0];
  const float* cell = (const float*)d_in[1];
  float* out = (float*)d_out;
  int n = in_sizes[0] / 3;
  int K = out_size / 6;

  char* ws = (char*)d_ws;
  size_t off = 0;
  auto alloc = [&](size_t bytes) -> char* {
    char* p = ws + off;
    off = (off + bytes + 255) & ~(size_t)255;
    return p;
  };
  // zeroed region first (single small memset): fill only
  int*    fill      = (int*)alloc((size_t)NCELLS * 4);              // 187 KB
  size_t  zbytes    = off;
  float4* wrapped   = (float4*)alloc((size_t)n * 16);               // 800 KB
  float4* cdata     = (float4*)alloc((size_t)NCELLS * SLOT * 16);   // 11.9 MB
  int2*   paddr     = (int2*)alloc((size_t)NB2 * BCAP * 8);         // 8.4 MB
  int*    blockSum  = (int*)alloc((size_t)NB2 * 4);                 // 8 KB
  int*    blockBase = (int*)alloc((size_t)NB2 * 4);                 // 8 KB
  if (off > ws_size) return;

  (void)hipMemsetAsync(fill, 0, zbytes, stream);
  int nb1 = (n + NT1 - 1) / NT1;
  k_build<<<nb1, NT1, 0, stream>>>(pos, cell, fill, wrapped, cdata, n);
  k_pair<<<NB2, NT2, 0, stream>>>(wrapped, fill, cdata, paddr, blockSum, n);
  k_scan<<<1, 1024, 0, stream>>>(blockSum, blockBase, out, K);
  k_emit<<<NB2, NT2, 0, stream>>>(wrapped, cdata, paddr, blockSum, blockBase, out, K);
}